// Round 8
// baseline (234.788 us; speedup 1.0000x reference)
//
#include <hip/hip_runtime.h>

typedef unsigned short u16;

#define NGRAPH 16
#define SEQ    1024
#define DIM    128
#define NHEAD  2
#define HDIM   64
#define KPOS   20
#define NTOT   (NGRAPH*SEQ)     // 16384
#define QKVD   (3*DIM)          // 384

// ---------- bf16 helpers ----------------------------------------------------
__device__ __forceinline__ float bf2f(u16 u) {
    return __uint_as_float(((unsigned int)u) << 16);
}
__device__ __forceinline__ u16 f2bf(float f) {
    unsigned int u = __float_as_uint(f);
    u += 0x7fffu + ((u >> 16) & 1u);   // RNE
    return (u16)(u >> 16);
}

// ---------- dtype-adaptive input loads (fbf=1: bf16, fbf=0: f32) -----------
__device__ __forceinline__ float ld1(const void* p, int fbf, size_t i) {
    return fbf ? bf2f(((const u16*)p)[i]) : ((const float*)p)[i];
}
// 8 contiguous weights -> packed bf16x8 (as float4 bit pattern)
__device__ __forceinline__ float4 ldw8(const void* W, int fbf, size_t i) {
    if (fbf) return *(const float4*)((const u16*)W + i);
    const float* q = (const float*)W + i;
    float4 a = *(const float4*)q, b = *(const float4*)(q + 4);
    float4 r;
    u16* d = (u16*)&r;
    d[0]=f2bf(a.x); d[1]=f2bf(a.y); d[2]=f2bf(a.z); d[3]=f2bf(a.w);
    d[4]=f2bf(b.x); d[5]=f2bf(b.y); d[6]=f2bf(b.z); d[7]=f2bf(b.w);
    return r;
}

// ---------- K0: dtype detection --------------------------------------------
__global__ void detect_kernel(const u16* __restrict__ x, int* __restrict__ flag) {
    if (threadIdx.x == 0 && blockIdx.x == 0) {
        int ok = 1;
        for (int i = 0; i < 256; i += 2) {
            unsigned e = (x[i] >> 7) & 0xFF;
            if (e < 60u || e > 180u) ok = 0;
        }
        *flag = ok;
    }
}

// ---------- K1: h0 = x + pos_enc @ pe_w.T + pe_b  (bf16, strided slots) ----
__global__ __launch_bounds__(256)
void pe_kernel(const void* __restrict__ x, const void* __restrict__ pos,
               const void* __restrict__ pe_w, const void* __restrict__ pe_b,
               u16* __restrict__ h0, const int* __restrict__ flag) {
    int fbf = *flag;
    __shared__ float wsh[DIM][KPOS + 1];
    int t = threadIdx.x;
    for (int i = t; i < DIM * KPOS; i += 256)
        wsh[i / KPOS][i % KPOS] = ld1(pe_w, fbf, i);
    __syncthreads();
    int row = blockIdx.x * 2 + (t >> 7), d = t & 127;
    float acc = 0.f;
#pragma unroll
    for (int k = 0; k < KPOS; ++k)
        acc += ld1(pos, fbf, (size_t)row * KPOS + k) * wsh[d][k];
    int rs = fbf ? 128 : 256;   // h0 row slot stride (u16 units)
    h0[(size_t)row * rs + d] =
        f2bf(ld1(x, fbf, (size_t)row * DIM + d) + acc + ld1(pe_b, fbf, d));
}

typedef __attribute__((ext_vector_type(8))) short bf16x8;
typedef __attribute__((ext_vector_type(4))) float f32x4;

// ---------- MFMA GEMM, K=128: out = A @ W^T (+epilogue) --------------------
// Block 256 = 4 waves; tile 64 rows x 128 cols. A-fragments load straight
// from global (no A staging); W staged once in LDS -> ONE barrier total.
// EPI 0: +bias -> bf16 ws (stride Mtot)
// EPI 2: +bias+resid+LN -> h01 slots (stride rs)
template<int EPI>
__global__ __launch_bounds__(256)
void mgemm_kernel(const u16* __restrict__ A, const void* __restrict__ W,
                  const void* __restrict__ bias, const u16* __restrict__ resid,
                  const void* __restrict__ lng, const void* __restrict__ lnb,
                  void* __restrict__ outp, int Mtot, int AstrIn,
                  int arow0, int orow0, const int* __restrict__ flag) {
    const int K = 128;
    int fbf  = *flag;
    int rs   = fbf ? 128 : 256;
    int Astr = (AstrIn < 0) ? rs : AstrIn;
    __shared__ u16 Wsh[128][136];   // [col][k] (+8 u16 pad, rows 16B-aligned)
    int t = threadIdx.x;
    int w = t >> 6, lane = t & 63, l16 = lane & 15, quad = lane >> 4;
    int n0 = blockIdx.x * 64;
    int m0 = blockIdx.y * 128;
    // A fragments: rows w*16+l16, k = kk*32+quad*8
    bf16x8 af[4];
#pragma unroll
    for (int kk = 0; kk < 4; ++kk)
        af[kk] = *(const bf16x8*)&A[(size_t)(arow0 + n0 + w * 16 + l16) * Astr
                                    + kk * 32 + quad * 8];
    // stage W tile 128x128
#pragma unroll
    for (int i = 0; i < 8; ++i) {
        int idx = t + i * 256;
        int m = idx >> 4, k8 = (idx & 15) * 8;
        *(float4*)&Wsh[m][k8] = ldw8(W, fbf, (size_t)(m0 + m) * K + k8);
    }
    __syncthreads();
    f32x4 acc[8] = {};
#pragma unroll
    for (int kk = 0; kk < 4; ++kk) {
#pragma unroll
        for (int s = 0; s < 8; ++s) {
            bf16x8 bf = *(const bf16x8*)&Wsh[s * 16 + l16][kk * 32 + quad * 8];
            acc[s] = __builtin_amdgcn_mfma_f32_16x16x32_bf16(af[kk], bf, acc[s], 0, 0, 0);
        }
    }
    // ---- epilogue ----
    float bb[8];
#pragma unroll
    for (int s = 0; s < 8; ++s) bb[s] = ld1(bias, fbf, m0 + s * 16 + l16);
    float gg[8], be[8];
    if (EPI == 2) {
#pragma unroll
        for (int s = 0; s < 8; ++s) {
            gg[s] = ld1(lng, fbf, s * 16 + l16);
            be[s] = ld1(lnb, fbf, s * 16 + l16);
        }
    }
#pragma unroll
    for (int r = 0; r < 4; ++r) {
        int lr = w * 16 + quad * 4 + r;
        float v[8];
#pragma unroll
        for (int s = 0; s < 8; ++s) v[s] = acc[s][r] + bb[s];
        if (EPI == 0) {
            u16* o = (u16*)outp;
#pragma unroll
            for (int s = 0; s < 8; ++s)
                o[(size_t)(n0 + lr) * Mtot + m0 + s * 16 + l16] = f2bf(v[s]);
        } else {
            size_t rg = (size_t)(orow0 + n0 + lr);
#pragma unroll
            for (int s = 0; s < 8; ++s)
                v[s] += bf2f(resid[rg * rs + s * 16 + l16]);
            float sm = 0.f, sq = 0.f;
#pragma unroll
            for (int s = 0; s < 8; ++s) { sm += v[s]; sq += v[s] * v[s]; }
#pragma unroll
            for (int off = 1; off < 16; off <<= 1) {
                sm += __shfl_xor(sm, off, 64);
                sq += __shfl_xor(sq, off, 64);
            }
            float mu  = sm * (1.f / DIM);
            float var = fmaxf(sq * (1.f / DIM) - mu * mu, 0.f);
            float rsq = rsqrtf(var + 1e-5f);
            u16* o = (u16*)outp;
#pragma unroll
            for (int s = 0; s < 8; ++s)
                o[rg * rs + s * 16 + l16] = f2bf((v[s] - mu) * rsq * gg[s] + be[s]);
        }
    }
}

// ---------- fused FF: out = LN( h1 + relu(h1@W1^T+b1)@W2^T + b2 ) ----------
// Block 256 = 4 waves, 64 rows/block. 4 chunks of 128 ff1-cols streamed
// through one LDS W buffer; f1 chunk kept wave-local in LDS (no barrier).
__global__ __launch_bounds__(256)
void ff_kernel(const u16* __restrict__ A, const void* __restrict__ W1,
               const void* __restrict__ b1, const void* __restrict__ W2,
               const void* __restrict__ b2, const void* __restrict__ lng,
               const void* __restrict__ lnb, void* __restrict__ outp,
               int arow0, const int* __restrict__ flag) {
    int fbf = *flag;
    int rs  = fbf ? 128 : 256;
    __shared__ u16 Wsh[128][136];
    __shared__ u16 f1sh[64][136];
    int t = threadIdx.x;
    int w = t >> 6, lane = t & 63, l16 = lane & 15, quad = lane >> 4;
    int n0 = blockIdx.x * 64;
    // A fragments (rows w*16+l16, K=128) from global
    bf16x8 af[4];
#pragma unroll
    for (int kk = 0; kk < 4; ++kk)
        af[kk] = *(const bf16x8*)&A[(size_t)(arow0 + n0 + w * 16 + l16) * rs
                                    + kk * 32 + quad * 8];
    f32x4 acc2[8] = {};
    // prefetch W1 chunk 0
    float4 wR[8];
#pragma unroll
    for (int i = 0; i < 8; ++i) {
        int idx = t + i * 256;
        int m = idx >> 4, k8 = (idx & 15) * 8;
        wR[i] = ldw8(W1, fbf, (size_t)m * 128 + k8);
    }
#pragma unroll 1
    for (int c = 0; c < 4; ++c) {
        // W1c regs -> LDS
#pragma unroll
        for (int i = 0; i < 8; ++i) {
            int idx = t + i * 256;
            *(float4*)&Wsh[idx >> 4][(idx & 15) * 8] = wR[i];
        }
        __syncthreads();
        // prefetch W2c (overlaps MFMA1)
#pragma unroll
        for (int i = 0; i < 8; ++i) {
            int idx = t + i * 256;
            int m = idx >> 4, k8 = (idx & 15) * 8;
            wR[i] = ldw8(W2, fbf, (size_t)m * 512 + c * 128 + k8);
        }
        // MFMA1: f1c = A @ W1c^T
        f32x4 acc1[8] = {};
#pragma unroll
        for (int kk = 0; kk < 4; ++kk) {
#pragma unroll
            for (int s = 0; s < 8; ++s) {
                bf16x8 bf = *(const bf16x8*)&Wsh[s * 16 + l16][kk * 32 + quad * 8];
                acc1[s] = __builtin_amdgcn_mfma_f32_16x16x32_bf16(af[kk], bf, acc1[s], 0, 0, 0);
            }
        }
        // bias+relu -> f1sh (wave-local rows, no barrier needed)
#pragma unroll
        for (int s = 0; s < 8; ++s) {
            float bb1 = ld1(b1, fbf, c * 128 + s * 16 + l16);
#pragma unroll
            for (int r = 0; r < 4; ++r)
                f1sh[w * 16 + quad * 4 + r][s * 16 + l16] =
                    f2bf(fmaxf(acc1[s][r] + bb1, 0.f));
        }
        __syncthreads();   // all waves done reading Wsh (W1c)
        // W2c regs -> LDS
#pragma unroll
        for (int i = 0; i < 8; ++i) {
            int idx = t + i * 256;
            *(float4*)&Wsh[idx >> 4][(idx & 15) * 8] = wR[i];
        }
        __syncthreads();
        // prefetch W1 chunk c+1 (overlaps MFMA2)
        if (c < 3) {
#pragma unroll
            for (int i = 0; i < 8; ++i) {
                int idx = t + i * 256;
                int m = idx >> 4, k8 = (idx & 15) * 8;
                wR[i] = ldw8(W1, fbf, (size_t)((c + 1) * 128 + m) * 128 + k8);
            }
        }
        // MFMA2: acc2 += f1c @ W2c^T
#pragma unroll
        for (int kk = 0; kk < 4; ++kk) {
            bf16x8 pf = *(const bf16x8*)&f1sh[w * 16 + l16][kk * 32 + quad * 8];
#pragma unroll
            for (int s = 0; s < 8; ++s) {
                bf16x8 bf = *(const bf16x8*)&Wsh[s * 16 + l16][kk * 32 + quad * 8];
                acc2[s] = __builtin_amdgcn_mfma_f32_16x16x32_bf16(pf, bf, acc2[s], 0, 0, 0);
            }
        }
        if (c < 3) __syncthreads();   // all waves done reading Wsh (W2c)
    }
    // ---- epilogue: +b2 +resid(A) + LN -> final out ----
    float bb2[8], gg[8], be[8];
#pragma unroll
    for (int s = 0; s < 8; ++s) {
        bb2[s] = ld1(b2, fbf, s * 16 + l16);
        gg[s]  = ld1(lng, fbf, s * 16 + l16);
        be[s]  = ld1(lnb, fbf, s * 16 + l16);
    }
#pragma unroll
    for (int r = 0; r < 4; ++r) {
        size_t rg = (size_t)(arow0 + n0 + w * 16 + quad * 4 + r);
        float v[8];
#pragma unroll
        for (int s = 0; s < 8; ++s)
            v[s] = acc2[s][r] + bb2[s] + bf2f(A[rg * rs + s * 16 + l16]);
        float sm = 0.f, sq = 0.f;
#pragma unroll
        for (int s = 0; s < 8; ++s) { sm += v[s]; sq += v[s] * v[s]; }
#pragma unroll
        for (int off = 1; off < 16; off <<= 1) {
            sm += __shfl_xor(sm, off, 64);
            sq += __shfl_xor(sq, off, 64);
        }
        float mu  = sm * (1.f / DIM);
        float var = fmaxf(sq * (1.f / DIM) - mu * mu, 0.f);
        float rsq = rsqrtf(var + 1e-5f);
        if (fbf) {
            u16* o = (u16*)outp;
#pragma unroll
            for (int s = 0; s < 8; ++s)
                o[rg * 128 + s * 16 + l16] = f2bf((v[s] - mu) * rsq * gg[s] + be[s]);
        } else {
            float* o = (float*)outp;
#pragma unroll
            for (int s = 0; s < 8; ++s)
                o[rg * 128 + s * 16 + l16] = (v[s] - mu) * rsq * gg[s] + be[s];
        }
    }
}

// ---------- K3: flash attention, MFMA bf16, double-buffered K/V ------------
// 1 barrier per k-tile. Q fragments straight from global (no Qsh).
__global__ __launch_bounds__(256)
void attn_kernel(const u16* __restrict__ qkv, u16* __restrict__ ctx) {
    __shared__ u16 Ksh[2][64][72];
    __shared__ u16 VshT[2][64][72];
    __shared__ u16 Psh[64][72];
    int t    = threadIdx.x;
    int w    = t >> 6;
    int lane = t & 63;
    int l16  = lane & 15;
    int quad = lane >> 4;
    int L = blockIdx.x;
    int ngh = gridDim.x >> 4;
    int qt, gh;
    if (ngh >= 8) {           // XCD swizzle: gh%8 == L%8
        int g8 = L & 7; int rest = L >> 3;
        qt = rest & 15; gh = (rest >> 4) * 8 + g8;
    } else {
        qt = L & 15; gh = L >> 4;
    }
    int b = gh >> 1, h = gh & 1;

    // Q fragments from global (rows qt*64 + w*16 + l16)
    bf16x8 qa0, qa1;
    {
        size_t n = (size_t)b * SEQ + qt * 64 + w * 16 + l16;
        qa0 = *(const bf16x8*)&qkv[n * QKVD + h * HDIM + quad * 8];
        qa1 = *(const bf16x8*)&qkv[n * QKVD + h * HDIM + 32 + quad * 8];
    }
    // prefetch K/V tile 0
    int kr = t >> 3, kd8 = (t & 7) * 8;
    int vr = t & 63, vdb = (t >> 6) * 16;
    float4 kR[2], vR[2];
    {
        size_t nk0 = (size_t)b * SEQ + kr;
        kR[0] = *(const float4*)&qkv[nk0 * QKVD + DIM + h * HDIM + kd8];
        kR[1] = *(const float4*)&qkv[(nk0 + 32) * QKVD + DIM + h * HDIM + kd8];
        size_t nv0 = (size_t)b * SEQ + vr;
        vR[0] = *(const float4*)&qkv[nv0 * QKVD + 2 * DIM + h * HDIM + vdb];
        vR[1] = *(const float4*)&qkv[nv0 * QKVD + 2 * DIM + h * HDIM + vdb + 8];
    }
    f32x4 o[4] = {};
    float mrow[4] = {-1e30f, -1e30f, -1e30f, -1e30f};
    float lrow[4] = {};
    const float SCL = 0.125f * 1.44269504f;   // 1/sqrt(64) * log2(e)

#pragma unroll 1
    for (int kt = 0; kt < SEQ / 64; ++kt) {
        int bi = kt & 1;
        *(float4*)&Ksh[bi][kr][kd8]      = kR[0];
        *(float4*)&Ksh[bi][kr + 32][kd8] = kR[1];
        {
            const u16* pa = (const u16*)&vR[0];
            const u16* pb = (const u16*)&vR[1];
#pragma unroll
            for (int j = 0; j < 8; ++j) VshT[bi][vdb + j][vr] = pa[j];
#pragma unroll
            for (int j = 0; j < 8; ++j) VshT[bi][vdb + 8 + j][vr] = pb[j];
        }
        __syncthreads();
        if (kt + 1 < SEQ / 64) {
            size_t nk0 = (size_t)b * SEQ + (kt + 1) * 64 + kr;
            kR[0] = *(const float4*)&qkv[nk0 * QKVD + DIM + h * HDIM + kd8];
            kR[1] = *(const float4*)&qkv[(nk0 + 32) * QKVD + DIM + h * HDIM + kd8];
            size_t nv0 = (size_t)b * SEQ + (kt + 1) * 64 + vr;
            vR[0] = *(const float4*)&qkv[nv0 * QKVD + 2 * DIM + h * HDIM + vdb];
            vR[1] = *(const float4*)&qkv[nv0 * QKVD + 2 * DIM + h * HDIM + vdb + 8];
        }
        float sc[4][4];
#pragma unroll
        for (int c = 0; c < 4; ++c) {
            bf16x8 kb0 = *(const bf16x8*)&Ksh[bi][c * 16 + l16][quad * 8];
            bf16x8 kb1 = *(const bf16x8*)&Ksh[bi][c * 16 + l16][32 + quad * 8];
            f32x4 s = {};
            s = __builtin_amdgcn_mfma_f32_16x16x32_bf16(qa0, kb0, s, 0, 0, 0);
            s = __builtin_amdgcn_mfma_f32_16x16x32_bf16(qa1, kb1, s, 0, 0, 0);
#pragma unroll
            for (int r = 0; r < 4; ++r) sc[c][r] = s[r] * SCL;   // log2-domain
        }
        float alpha[4];
#pragma unroll
        for (int r = 0; r < 4; ++r) {
            float mx = fmaxf(fmaxf(sc[0][r], sc[1][r]), fmaxf(sc[2][r], sc[3][r]));
#pragma unroll
            for (int off = 1; off < 16; off <<= 1)
                mx = fmaxf(mx, __shfl_xor(mx, off, 64));
            float mnew = fmaxf(mrow[r], mx);
            alpha[r] = exp2f(mrow[r] - mnew);
            mrow[r] = mnew;
            float sum = 0.f;
#pragma unroll
            for (int c = 0; c < 4; ++c) {
                float p = exp2f(sc[c][r] - mnew);
                sc[c][r] = p;
                sum += p;
            }
#pragma unroll
            for (int off = 1; off < 16; off <<= 1)
                sum += __shfl_xor(sum, off, 64);
            lrow[r] = lrow[r] * alpha[r] + sum;
        }
#pragma unroll
        for (int c = 0; c < 4; ++c)
#pragma unroll
            for (int r = 0; r < 4; ++r)
                Psh[w * 16 + quad * 4 + r][c * 16 + l16] = f2bf(sc[c][r]);
#pragma unroll
        for (int dt = 0; dt < 4; ++dt)
#pragma unroll
            for (int r = 0; r < 4; ++r) o[dt][r] *= alpha[r];
        bf16x8 pa0 = *(const bf16x8*)&Psh[w * 16 + l16][quad * 8];
        bf16x8 pa1 = *(const bf16x8*)&Psh[w * 16 + l16][32 + quad * 8];
#pragma unroll
        for (int dt = 0; dt < 4; ++dt) {
            bf16x8 vb0 = *(const bf16x8*)&VshT[bi][dt * 16 + l16][quad * 8];
            bf16x8 vb1 = *(const bf16x8*)&VshT[bi][dt * 16 + l16][32 + quad * 8];
            o[dt] = __builtin_amdgcn_mfma_f32_16x16x32_bf16(pa0, vb0, o[dt], 0, 0, 0);
            o[dt] = __builtin_amdgcn_mfma_f32_16x16x32_bf16(pa1, vb1, o[dt], 0, 0, 0);
        }
    }
#pragma unroll
    for (int r = 0; r < 4; ++r) {
        float inv = 1.f / lrow[r];
        size_t n = (size_t)b * SEQ + qt * 64 + w * 16 + quad * 4 + r;
#pragma unroll
        for (int dt = 0; dt < 4; ++dt)
            ctx[n * DIM + h * HDIM + dt * 16 + l16] = f2bf(o[dt][r] * inv);
    }
}

// ---------------------------------------------------------------------------
extern "C" void kernel_launch(void* const* d_in, const int* in_sizes, int n_in,
                              void* d_out, int out_size, void* d_ws, size_t ws_size,
                              hipStream_t stream) {
    const void* x     = d_in[0];
    const void* pos   = d_in[1];
    const void* pe_w  = d_in[2];
    const void* pe_b  = d_in[3];
    const void* in_w  = d_in[4];
    const void* in_b  = d_in[5];
    const void* out_w = d_in[6];
    const void* out_b = d_in[7];
    const void* ln1_g = d_in[8];
    const void* ln1_b = d_in[9];
    const void* ln2_g = d_in[10];
    const void* ln2_b = d_in[11];
    const void* ff1_w = d_in[12];
    const void* ff1_b = d_in[13];
    const void* ff2_w = d_in[14];
    const void* ff2_b = d_in[15];

    char* wsb  = (char*)d_ws;
    int*  flag = (int*)(wsb + ((ws_size - 4) & ~(size_t)3));
    u16*  h01  = (u16*)d_out;   // h0 then h1, bf16 in dtype-dependent row slots
    const size_t MB = 1024 * 1024;

    detect_kernel<<<1, 1, 0, stream>>>((const u16*)x, flag);
    pe_kernel<<<NTOT / 2, 256, 0, stream>>>(x, pos, pe_w, pe_b, h01, flag);

    if (ws_size >= 17 * MB) {
        // batched: qkv[0,12M), ctx[12M,16M)
        u16* qkv = (u16*)wsb;
        u16* ctx = (u16*)(wsb + 12 * MB);
        mgemm_kernel<0><<<dim3(NTOT / 64, 3), 256, 0, stream>>>(
            h01, in_w, in_b, nullptr, nullptr, nullptr, qkv,
            QKVD, -1, 0, 0, flag);
        attn_kernel<<<NGRAPH * NHEAD * 16, 256, 0, stream>>>(qkv, ctx);
        mgemm_kernel<2><<<dim3(NTOT / 64, 1), 256, 0, stream>>>(
            ctx, out_w, out_b, h01, ln1_g, ln1_b, h01,
            DIM, DIM, 0, 0, flag);
        ff_kernel<<<NTOT / 64, 256, 0, stream>>>(
            h01, ff1_w, ff1_b, ff2_w, ff2_b, ln2_g, ln2_b, d_out, 0, flag);
    } else {
        // per-graph: qkv_g[0,768K), ctx_g[768K,1M)
        u16* qkv_g = (u16*)wsb;
        u16* ctx_g = (u16*)(wsb + 768 * 1024);
        for (int g = 0; g < NGRAPH; ++g) {
            int row0 = g * SEQ;
            mgemm_kernel<0><<<dim3(SEQ / 64, 3), 256, 0, stream>>>(
                h01, in_w, in_b, nullptr, nullptr, nullptr, qkv_g,
                QKVD, -1, row0, 0, flag);
            attn_kernel<<<NHEAD * 16, 256, 0, stream>>>(qkv_g, ctx_g);
            mgemm_kernel<2><<<dim3(SEQ / 64, 1), 256, 0, stream>>>(
                ctx_g, out_w, out_b, h01, ln1_g, ln1_b, h01,
                DIM, DIM, 0, row0, flag);
        }
        for (int g = 0; g < NGRAPH; ++g) {
            int row0 = g * SEQ;
            ff_kernel<<<SEQ / 64, 256, 0, stream>>>(
                h01, ff1_w, ff1_b, ff2_w, ff2_b, ln2_g, ln2_b, d_out, row0, flag);
        }
    }
}